// Round 1
// baseline (23233.757 us; speedup 1.0000x reference)
//
#include <hip/hip_runtime.h>
#include <math.h>

#define Bq 8192
#define BB 4
#define NBLK (Bq/BB)

// ws float offsets
#define WSUMS 0
#define TOTWS 1
#define WSUM_OFF 2
#define TOTW_OFF (2+Bq)
#define OFF_GI 16640            // gru WihT  [30][384]
#define OFF_GH 28160            // gru WhhT  [128][384]
#define OFF_EI 77312            // enc WihT  [7][128][512]
#define OFF_EH 536064           // enc WhhT  [7][128][512]
#define OFF_DI 994816           // dec WihT  [180][512]
#define OFF_DH 1086976          // dec WhhT  [128][512]

__device__ __forceinline__ float sig_(float x){ return 1.0f/(1.0f+__expf(-x)); }
__device__ __forceinline__ float th_(float x){ float e=__expf(2.0f*x); return 1.0f - 2.0f/(e+1.0f); }

__global__ void scale_kernel(const float* __restrict__ tgt,
                             const float* __restrict__ obs,
                             float* __restrict__ ws)
{
  __shared__ float s1[256], s2[256];
  int b = blockIdx.x*256 + threadIdx.x;
  float wsum=0.f, totw=0.f;
  const float* tr = tgt + b*336 + 168;
  const float* wr = obs + b*336 + 168;
  for(int t=0;t<168;t++){ float w=wr[t]; wsum += fabsf(tr[t])*w; totw += w; }
  ws[WSUM_OFF + b] = wsum;
  ws[TOTW_OFF + b] = totw;
  s1[threadIdx.x]=wsum; s2[threadIdx.x]=totw;
  __syncthreads();
  for(int s=128;s>0;s>>=1){
    if(threadIdx.x<s){ s1[threadIdx.x]+=s1[threadIdx.x+s]; s2[threadIdx.x]+=s2[threadIdx.x+s]; }
    __syncthreads();
  }
  if(threadIdx.x==0){ atomicAdd(&ws[WSUMS], s1[0]); atomicAdd(&ws[TOTWS], s2[0]); }
}

__global__ void prep_kernel(const float* __restrict__ gWih, const float* __restrict__ gWhh,
                            const float* __restrict__ eWih, const float* __restrict__ eWhh,
                            const float* __restrict__ dWih, const float* __restrict__ dWhh,
                            float* __restrict__ ws)
{
  int tid = blockIdx.x*blockDim.x + threadIdx.x;
  int nt = gridDim.x*blockDim.x;
  for(int i=tid;i<384*30;i+=nt){ int n=i/30, k=i-n*30; ws[OFF_GI + k*384+n]=gWih[i]; }
  for(int i=tid;i<384*128;i+=nt){ int n=i>>7, k=i&127; ws[OFF_GH + k*384+n]=gWhh[i]; }
  for(int i=tid;i<7*512*128;i+=nt){ int s=i>>16, rr=i&65535; int n=rr>>7, k=rr&127; ws[OFF_EI + s*65536 + k*512+n]=eWih[i]; }
  for(int i=tid;i<7*512*128;i+=nt){ int s=i>>16, rr=i&65535; int n=rr>>7, k=rr&127; ws[OFF_EH + s*65536 + k*512+n]=eWhh[i]; }
  for(int i=tid;i<512*180;i+=nt){ int n=i/180, k=i-n*180; ws[OFF_DI + k*512+n]=dWih[i]; }
  for(int i=tid;i<512*128;i+=nt){ int n=i>>7, k=i&127; ws[OFF_DH + k*512+n]=dWhh[i]; }
}

__global__ __launch_bounds__(256,2)
void deepar_main(const int* __restrict__ cat, const float* __restrict__ sreal,
                 const float* __restrict__ ptf, const float* __restrict__ tgt,
                 const float* __restrict__ ftf, const float* __restrict__ emb,
                 const float* __restrict__ gbih, const float* __restrict__ gbhh,
                 const float* __restrict__ encb, const float* __restrict__ decb,
                 const float* __restrict__ outW, const float* __restrict__ outb,
                 const float* __restrict__ ws, float* __restrict__ out)
{
  __shared__ float buf[BB*24*128];   // enc_out / hv, updated in place
  __shared__ float gb[BB*512];       // lstm gate exchange
  __shared__ float hs[BB*128];
  __shared__ float cs[BB*128];
  __shared__ float stat[BB][18];
  __shared__ float scl[BB];
  __shared__ float invs[BB];

  const int tid = threadIdx.x;
  const int b0 = blockIdx.x*BB;
  const int LAGOFF[8] = {144,120,96,72,48,24,0,168}; // 168 - lag

  if(tid < BB){
    int b = b0+tid;
    float wsum = ws[WSUM_OFF+b], totw = ws[TOTW_OFF+b];
    float def = ws[WSUMS]/fmaxf(ws[TOTWS],1.f);
    float sc = (wsum>0.f) ? (wsum/fmaxf(totw,1.f)) : def;
    sc = fmaxf(1e-10f, sc);
    scl[tid]=sc; invs[tid]=1.f/sc;
  }
  if(tid >= 64 && tid < 64 + BB*16){
    int q = tid-64; int r=q>>4, k=q&15;
    stat[r][k] = emb[cat[b0+r]*16 + k];
  }
  for(int i=tid;i<BB*24*128;i+=256) buf[i]=0.f;
  for(int i=tid;i<BB*128;i+=256){ hs[i]=0.f; cs[i]=0.f; }
  __syncthreads();
  if(tid < BB){ stat[tid][16]=sreal[b0+tid]; stat[tid][17]=logf(scl[tid]); }
  __syncthreads();

  const int j = tid & 127, hf = tid >> 7;
  const float bi0=gbih[j], bi1=gbih[128+j], bi2=gbih[256+j];
  const float bh0=gbhh[j], bh1=gbhh[128+j], bh2=gbhh[256+j];
  const float* __restrict__ WgiT = ws + OFF_GI;
  const float* __restrict__ WghT = ws + OFF_GH;

  for(int seg=0; seg<7; seg++){
    // ---------------- GRU over all 24 positions of this segment ----------------
    for(int chunk=0; chunk<6; chunk++){
      const int m0 = hf*48 + chunk*8;           // 8 consecutive rows, same batch r
      const int r = m0/24, t0 = m0 - r*24;
      const int b = b0 + r;
      const float iscale = invs[r];
      const float* trow = tgt + b*336 + seg*24 + t0;
      const float* prow = ptf + (b*336 + 168 + seg*24 + t0)*4;
      float g0[8],g1[8],g2[8],h0[8],h1[8],h2[8];
      #pragma unroll
      for(int i=0;i<8;i++){ g0[i]=bi0; g1[i]=bi1; g2[i]=bi2; h0[i]=bh0; h1[i]=bh1; h2[i]=bh2; }
      #pragma unroll
      for(int k=0;k<8;k++){
        const float* wp = WgiT + k*384;
        float w0=wp[j], w1=wp[128+j], w2=wp[256+j];
        #pragma unroll
        for(int i=0;i<8;i++){
          float xv = trow[LAGOFF[k]+i]*iscale;
          g0[i]=fmaf(xv,w0,g0[i]); g1[i]=fmaf(xv,w1,g1[i]); g2[i]=fmaf(xv,w2,g2[i]);
        }
      }
      #pragma unroll
      for(int k=0;k<4;k++){
        const float* wp = WgiT + (8+k)*384;
        float w0=wp[j], w1=wp[128+j], w2=wp[256+j];
        #pragma unroll
        for(int i=0;i<8;i++){
          float xv = prow[i*4+k];
          g0[i]=fmaf(xv,w0,g0[i]); g1[i]=fmaf(xv,w1,g1[i]); g2[i]=fmaf(xv,w2,g2[i]);
        }
      }
      #pragma unroll
      for(int k=0;k<18;k++){
        const float* wp = WgiT + (12+k)*384;
        float w0=wp[j], w1=wp[128+j], w2=wp[256+j];
        float xv = stat[r][k];
        #pragma unroll
        for(int i=0;i<8;i++){ g0[i]=fmaf(xv,w0,g0[i]); g1[i]=fmaf(xv,w1,g1[i]); g2[i]=fmaf(xv,w2,g2[i]); }
      }
      #pragma unroll 4
      for(int k=0;k<128;k++){
        const float* wp = WghT + k*384;
        float w0=wp[j], w1=wp[128+j], w2=wp[256+j];
        #pragma unroll
        for(int i=0;i<8;i++){
          float hv = buf[(m0+i)*128+k];
          h0[i]=fmaf(hv,w0,h0[i]); h1[i]=fmaf(hv,w1,h1[i]); h2[i]=fmaf(hv,w2,h2[i]);
        }
      }
      float hvn[8];
      #pragma unroll
      for(int i=0;i<8;i++){
        float rg = sig_(g0[i]+h0[i]);
        float zg = sig_(g1[i]+h1[i]);
        float ng = th_(g2[i] + rg*h2[i]);
        hvn[i] = (1.f-zg)*ng + zg*buf[(m0+i)*128+j];
      }
      __syncthreads();
      #pragma unroll
      for(int i=0;i<8;i++) buf[(m0+i)*128+j] = hvn[i];
      __syncthreads();
    }

    // ---------------- encoder LSTM, 24 sequential steps ----------------
    const float* __restrict__ WeiT = ws + OFF_EI + seg*65536;
    const float* __restrict__ WehT = ws + OFF_EH + seg*65536;
    const int n0 = tid*2;
    const float be0 = encb[seg*512+n0], be1 = encb[seg*512+n0+1];
    for(int t=0;t<24;t++){
      float a0[4], a1[4];
      #pragma unroll
      for(int r=0;r<4;r++){ a0[r]=be0; a1[r]=be1; }
      #pragma unroll 8
      for(int k=0;k<128;k++){
        float2 w = *reinterpret_cast<const float2*>(WeiT + k*512 + n0);
        #pragma unroll
        for(int r=0;r<4;r++){
          float xv = buf[(r*24+t)*128+k];
          a0[r]=fmaf(xv,w.x,a0[r]); a1[r]=fmaf(xv,w.y,a1[r]);
        }
      }
      #pragma unroll 8
      for(int k=0;k<128;k++){
        float2 w = *reinterpret_cast<const float2*>(WehT + k*512 + n0);
        #pragma unroll
        for(int r=0;r<4;r++){
          float hv = hs[r*128+k];
          a0[r]=fmaf(hv,w.x,a0[r]); a1[r]=fmaf(hv,w.y,a1[r]);
        }
      }
      #pragma unroll
      for(int r=0;r<4;r++){ gb[r*512+n0]=a0[r]; gb[r*512+n0+1]=a1[r]; }
      __syncthreads();
      {
        const int jj = tid & 127, rr = tid >> 7;
        #pragma unroll
        for(int q=0;q<2;q++){
          int r = rr + 2*q;
          float ig = sig_(gb[r*512+jj]);
          float fg = sig_(gb[r*512+128+jj]);
          float gg = th_(gb[r*512+256+jj]);
          float og = sig_(gb[r*512+384+jj]);
          float c_ = fg*cs[r*128+jj] + ig*gg;
          float h_ = og*th_(c_);
          cs[r*128+jj]=c_; hs[r*128+jj]=h_;
          buf[(r*24+t)*128+jj]=h_;
        }
      }
      __syncthreads();
    }
  }

  // ---------------- decoder LSTM + projection ----------------
  {
    const float* __restrict__ WdiT = ws + OFF_DI;
    const float* __restrict__ WdhT = ws + OFF_DH;
    const int n0 = tid*2;
    const float bd0 = decb[n0], bd1 = decb[n0+1];
    const float outw_b = outb[0];
    for(int t=0;t<24;t++){
      float a0[4], a1[4];
      #pragma unroll
      for(int r=0;r<4;r++){ a0[r]=bd0; a1[r]=bd1; }
      // query[0:8): seg-0 lags
      #pragma unroll
      for(int k=0;k<8;k++){
        float2 w = *reinterpret_cast<const float2*>(WdiT + k*512 + n0);
        #pragma unroll
        for(int r=0;r<4;r++){
          float xv = tgt[(b0+r)*336 + LAGOFF[k] + t]*invs[r];
          a0[r]=fmaf(xv,w.x,a0[r]); a1[r]=fmaf(xv,w.y,a1[r]);
        }
      }
      // query[8:12): seg-0 time feat
      #pragma unroll
      for(int k=0;k<4;k++){
        float2 w = *reinterpret_cast<const float2*>(WdiT + (8+k)*512 + n0);
        #pragma unroll
        for(int r=0;r<4;r++){
          float xv = ptf[((b0+r)*336 + 168 + t)*4 + k];
          a0[r]=fmaf(xv,w.x,a0[r]); a1[r]=fmaf(xv,w.y,a1[r]);
        }
      }
      // query[12:30): static
      #pragma unroll
      for(int k=0;k<18;k++){
        float2 w = *reinterpret_cast<const float2*>(WdiT + (12+k)*512 + n0);
        #pragma unroll
        for(int r=0;r<4;r++){
          float xv = stat[r][k];
          a0[r]=fmaf(xv,w.x,a0[r]); a1[r]=fmaf(xv,w.y,a1[r]);
        }
      }
      // query[30:158): encoder_out (final)
      #pragma unroll 8
      for(int k=0;k<128;k++){
        float2 w = *reinterpret_cast<const float2*>(WdiT + (30+k)*512 + n0);
        #pragma unroll
        for(int r=0;r<4;r++){
          float xv = buf[(r*24+t)*128+k];
          a0[r]=fmaf(xv,w.x,a0[r]); a1[r]=fmaf(xv,w.y,a1[r]);
        }
      }
      // query[158:162): future time feat
      #pragma unroll
      for(int k=0;k<4;k++){
        float2 w = *reinterpret_cast<const float2*>(WdiT + (158+k)*512 + n0);
        #pragma unroll
        for(int r=0;r<4;r++){
          float xv = ftf[(b0+r)*96 + t*4 + k];
          a0[r]=fmaf(xv,w.x,a0[r]); a1[r]=fmaf(xv,w.y,a1[r]);
        }
      }
      // query[162:180): static again
      #pragma unroll
      for(int k=0;k<18;k++){
        float2 w = *reinterpret_cast<const float2*>(WdiT + (162+k)*512 + n0);
        #pragma unroll
        for(int r=0;r<4;r++){
          float xv = stat[r][k];
          a0[r]=fmaf(xv,w.x,a0[r]); a1[r]=fmaf(xv,w.y,a1[r]);
        }
      }
      // recurrent part
      #pragma unroll 8
      for(int k=0;k<128;k++){
        float2 w = *reinterpret_cast<const float2*>(WdhT + k*512 + n0);
        #pragma unroll
        for(int r=0;r<4;r++){
          float hv = hs[r*128+k];
          a0[r]=fmaf(hv,w.x,a0[r]); a1[r]=fmaf(hv,w.y,a1[r]);
        }
      }
      #pragma unroll
      for(int r=0;r<4;r++){ gb[r*512+n0]=a0[r]; gb[r*512+n0+1]=a1[r]; }
      __syncthreads();
      {
        const int jj = tid & 127, rr = tid >> 7;
        #pragma unroll
        for(int q=0;q<2;q++){
          int r = rr + 2*q;
          float ig = sig_(gb[r*512+jj]);
          float fg = sig_(gb[r*512+128+jj]);
          float gg = th_(gb[r*512+256+jj]);
          float og = sig_(gb[r*512+384+jj]);
          float c_ = fg*cs[r*128+jj] + ig*gg;
          float h_ = og*th_(c_);
          cs[r*128+jj]=c_; hs[r*128+jj]=h_;
        }
      }
      __syncthreads();
      {
        const int wv = tid >> 6, l = tid & 63;
        float p = hs[wv*128+l]*outW[l] + hs[wv*128+64+l]*outW[64+l];
        #pragma unroll
        for(int off=32;off>0;off>>=1) p += __shfl_down(p, off);
        if(l==0) out[(b0+wv)*24+t] = (p + outw_b)*scl[wv];
      }
      __syncthreads();
    }
  }
}

extern "C" void kernel_launch(void* const* d_in, const int* in_sizes, int n_in,
                              void* d_out, int out_size, void* d_ws, size_t ws_size,
                              hipStream_t stream)
{
  (void)in_sizes; (void)n_in; (void)out_size; (void)ws_size;
  const int*   cat  = (const int*)d_in[0];
  const float* sreal= (const float*)d_in[1];
  const float* ptf  = (const float*)d_in[2];
  const float* tgt  = (const float*)d_in[3];
  const float* obs  = (const float*)d_in[4];
  const float* ftf  = (const float*)d_in[5];
  const float* emb  = (const float*)d_in[6];
  const float* gWih = (const float*)d_in[7];
  const float* gWhh = (const float*)d_in[8];
  const float* gbih = (const float*)d_in[9];
  const float* gbhh = (const float*)d_in[10];
  const float* eWih = (const float*)d_in[11];
  const float* eWhh = (const float*)d_in[12];
  const float* encb = (const float*)d_in[13];
  const float* dWih = (const float*)d_in[14];
  const float* dWhh = (const float*)d_in[15];
  const float* decb = (const float*)d_in[16];
  const float* outW = (const float*)d_in[17];
  const float* outb = (const float*)d_in[18];
  float* ws  = (float*)d_ws;
  float* out = (float*)d_out;

  hipMemsetAsync(d_ws, 0, 2*sizeof(float), stream);
  scale_kernel<<<dim3(Bq/256), dim3(256), 0, stream>>>(tgt, obs, ws);
  prep_kernel<<<dim3(2048), dim3(256), 0, stream>>>(gWih,gWhh,eWih,eWhh,dWih,dWhh,ws);
  deepar_main<<<dim3(NBLK), dim3(256), 0, stream>>>(cat,sreal,ptf,tgt,ftf,emb,
                                                    gbih,gbhh,encb,decb,outW,outb,ws,out);
}

// Round 2
// 3142.809 us; speedup vs baseline: 7.3927x; 7.3927x over previous
//
#include <hip/hip_runtime.h>
#include <math.h>

typedef short bf16x8 __attribute__((ext_vector_type(8)));
typedef float f32x4 __attribute__((ext_vector_type(4)));
typedef unsigned short u16;
typedef unsigned int u32;

#define WSUMS 0
#define TOTWS 1
#define WSUM_OFF 2
#define TOTW_OFF 8194
// bf16 weight region starts at byte 66560 (float idx 16640)
#define WB_BYTE 66560
#define GI_U 0              // [384][32]
#define GH_U 12288          // [384][128]
#define EO_U 61440          // [7][512][256]
#define DO_U 978944         // [512][320]
#define BUF_BYTE 2425856    // hv/enc_out ring: [8192][24][128] bf16
#define BUF_BYTES 50331648

__constant__ int cLAG[8] = {144,120,96,72,48,24,0,168};

__device__ __forceinline__ float sig_(float x){ return 1.0f/(1.0f+__expf(-x)); }
__device__ __forceinline__ float th_(float x){ float e=__expf(2.0f*x); return 1.0f - 2.0f/(e+1.0f); }
__device__ __forceinline__ u16 f2b(float x){ u32 u=__float_as_uint(x); return (u16)((u + 0x7fffu + ((u>>16)&1u))>>16); }
__device__ __forceinline__ float b2f(u16 v){ return __uint_as_float(((u32)v)<<16); }

__global__ void scale_kernel(const float* __restrict__ tgt,
                             const float* __restrict__ obs,
                             float* __restrict__ ws)
{
  __shared__ float s1[256], s2[256];
  int b = blockIdx.x*256 + threadIdx.x;
  float wsum=0.f, totw=0.f;
  const float* tr = tgt + b*336 + 168;
  const float* wr = obs + b*336 + 168;
  for(int t=0;t<168;t++){ float w=wr[t]; wsum += fabsf(tr[t])*w; totw += w; }
  ws[WSUM_OFF + b] = wsum;
  ws[TOTW_OFF + b] = totw;
  s1[threadIdx.x]=wsum; s2[threadIdx.x]=totw;
  __syncthreads();
  for(int s=128;s>0;s>>=1){
    if(threadIdx.x<s){ s1[threadIdx.x]+=s1[threadIdx.x+s]; s2[threadIdx.x]+=s2[threadIdx.x+s]; }
    __syncthreads();
  }
  if(threadIdx.x==0){ atomicAdd(&ws[WSUMS], s1[0]); atomicAdd(&ws[TOTWS], s2[0]); }
}

// Build bf16 transposed weight tables: B[n][k], k contiguous.
__global__ void prep_kernel(const float* __restrict__ gWih, const float* __restrict__ gWhh,
                            const float* __restrict__ eWih, const float* __restrict__ eWhh,
                            const float* __restrict__ dWih, const float* __restrict__ dWhh,
                            float* __restrict__ ws)
{
  u16* WU = (u16*)((char*)ws + WB_BYTE);
  int tid = blockIdx.x*blockDim.x + threadIdx.x;
  int nt = gridDim.x*blockDim.x;
  for(int i=tid;i<12288;i+=nt){ int n=i>>5, k=i&31; WU[GI_U+i] = (k<30)? f2b(gWih[n*30+k]) : 0; }
  for(int i=tid;i<49152;i+=nt){ int n=i>>7, k=i&127; WU[GH_U+i] = f2b(gWhh[n*128+k]); }
  for(int i=tid;i<917504;i+=nt){
    int s=i>>17, r2=i&131071; int n=r2>>8, k=r2&255;
    float v = (k<128)? eWih[(s*512+n)*128+k] : eWhh[(s*512+n)*128+(k-128)];
    WU[EO_U+i] = f2b(v);
  }
  for(int i=tid;i<163840;i+=nt){
    int n=i/320, k=i-n*320; float v;
    if(k<30)        v = dWih[n*180+k];
    else if(k<32)   v = 0.f;
    else if(k<160)  v = dWih[n*180+30+(k-32)];
    else if(k<164)  v = dWih[n*180+158+(k-160)];
    else if(k<182)  v = dWih[n*180+162+(k-164)];
    else if(k<192)  v = 0.f;
    else            v = dWhh[n*128+(k-192)];
    WU[DO_U+i] = f2b(v);
  }
}

#define MFMA(a,b,c) __builtin_amdgcn_mfma_f32_16x16x32_bf16(a,b,c,0,0,0)

__global__ __launch_bounds__(512,2)
void deepar_mfma(const int* __restrict__ cat, const float* __restrict__ sreal,
                 const float* __restrict__ ptf, const float* __restrict__ tgt,
                 const float* __restrict__ ftf, const float* __restrict__ emb,
                 const float* __restrict__ gbih, const float* __restrict__ gbhh,
                 const float* __restrict__ encb, const float* __restrict__ decb,
                 const float* __restrict__ outW, const float* __restrict__ outb,
                 float* __restrict__ ws, float* __restrict__ out)
{
  const u16* __restrict__ WU = (const u16*)((const char*)ws + WB_BYTE);
  u16* __restrict__ BUF = (u16*)((char*)ws + BUF_BYTE);

  __shared__ __align__(16) u16 Ast[10752];      // GRU: [64][168]; enc: [32][136]; dec: [32][200]
  __shared__ __align__(16) u16 hstash[32*136];  // recurrent h, bf16, padded pitch
  __shared__ u16 statb[32][18];
  __shared__ float scl[32], invs[32];
  __shared__ float outw_s[128];
  __shared__ float red[32][8];
  __shared__ float outb_s;

  const int tid = threadIdx.x;
  const int b0 = blockIdx.x*32;
  const int wv = tid>>6, lane = tid&63, quad = lane>>4, l15 = lane&15;

  if(tid<32){
    float wsumv = ws[WSUM_OFF+b0+tid], totw = ws[TOTW_OFF+b0+tid];
    float def = ws[WSUMS]/fmaxf(ws[TOTWS],1.f);
    float sc = fmaxf(1e-10f, (wsumv>0.f)? wsumv/fmaxf(totw,1.f) : def);
    scl[tid]=sc; invs[tid]=1.f/sc;
  }
  { int r = tid>>4, k = tid&15; statb[r][k] = f2b(emb[cat[b0+r]*16+k]); }
  if(tid<128) outw_s[tid]=outW[tid];
  if(tid==128) outb_s = outb[0];
  for(int i=tid;i<32*136;i+=512) hstash[i]=0;
  __syncthreads();
  if(tid<32){ statb[tid][16]=f2b(sreal[b0+tid]); statb[tid][17]=f2b(logf(scl[tid])); }
  __syncthreads();

  float cst[2][4];
  #pragma unroll
  for(int m=0;m<2;m++)
    #pragma unroll
    for(int r=0;r<4;r++) cst[m][r]=0.f;

  float bi3[3], bh3[3];
  #pragma unroll
  for(int nt=0;nt<3;nt++){ int nb=(wv+nt*8)*16+l15; bi3[nt]=gbih[nb]; bh3[nt]=gbhh[nb]; }

  for(int seg=0; seg<7; seg++){
    // =============== GRU: batched over all 24 t (not sequential) ===============
    for(int chunk=0; chunk<12; chunk++){
      __syncthreads();
      // stage x-part [64][k<32]
      #pragma unroll
      for(int q=0;q<4;q++){
        int e=tid*4+q; int a=e>>5, kk=e&31; int ar=chunk*64+a; int r=ar/24, t=ar-r*24;
        u16 v;
        if(kk<8)       v = f2b(tgt[(b0+r)*336 + seg*24 + t + cLAG[kk]]*invs[r]);
        else if(kk<12) v = f2b(ptf[((size_t)((b0+r)*336+168+seg*24+t))*4 + (kk-8)]);
        else if(kk<30) v = statb[r][kk-12];
        else           v = 0;
        Ast[a*168+kk]=v;
      }
      // stage h-part (prev enc_out) from global ring, contiguous
      { const uint4* src = (const uint4*)(BUF + ((size_t)(b0*24 + chunk*64))*128);
        #pragma unroll
        for(int q=0;q<2;q++){ int idx=tid*2+q; int i=idx*8; int a=i>>7, c=i&127;
          *(uint4*)(&Ast[a*168+32+c]) = src[idx]; } }
      __syncthreads();

      f32x4 ai[3][4], ah[3][4];
      #pragma unroll
      for(int nt=0;nt<3;nt++)
        #pragma unroll
        for(int mt=0;mt<4;mt++)
          #pragma unroll
          for(int r=0;r<4;r++){ ai[nt][mt][r]=bi3[nt]; ah[nt][mt][r]=bh3[nt]; }

      bf16x8 axf[4];
      #pragma unroll
      for(int mt=0;mt<4;mt++) axf[mt] = *(const bf16x8*)(&Ast[(mt*16+l15)*168 + quad*8]);

      #pragma unroll
      for(int nt=0;nt<3;nt++){
        int nb=(wv+nt*8)*16+l15;
        bf16x8 bf = *(const bf16x8*)(WU + GI_U + nb*32 + quad*8);
        #pragma unroll
        for(int mt=0;mt<4;mt++) ai[nt][mt]=MFMA(axf[mt], bf, ai[nt][mt]);
        const u16* bh = WU + GH_U + nb*128 + quad*8;
        #pragma unroll
        for(int kt=0;kt<4;kt++){
          bf16x8 bfh = *(const bf16x8*)(bh + kt*32);
          #pragma unroll
          for(int mt=0;mt<4;mt++){
            bf16x8 af = *(const bf16x8*)(&Ast[(mt*16+l15)*168 + 32 + kt*32 + quad*8]);
            ah[nt][mt]=MFMA(af, bfh, ah[nt][mt]);
          }
        }
      }
      // GRU cell (lane-local; gates r,z,n in nt=0,1,2)
      #pragma unroll
      for(int mt=0;mt<4;mt++)
        #pragma unroll
        for(int reg=0;reg<4;reg++){
          int arow = mt*16 + quad*4 + reg;
          int hcol = wv*16 + l15;
          float rg = sig_(ai[0][mt][reg]+ah[0][mt][reg]);
          float zg = sig_(ai[1][mt][reg]+ah[1][mt][reg]);
          float hp = b2f(Ast[arow*168+32+hcol]);
          float nn = th_(ai[2][mt][reg] + rg*ah[2][mt][reg]);
          float hv = (1.f-zg)*nn + zg*hp;
          BUF[((size_t)(b0*24 + chunk*64 + arow))*128 + hcol] = f2b(hv);
        }
    }
    __syncthreads();

    // =============== encoder LSTM: 24 sequential steps ===============
    float be[4];
    #pragma unroll
    for(int j=0;j<4;j++) be[j]=encb[seg*512+(wv+j*8)*16+l15];
    const u16* __restrict__ bbase = WU + EO_U + (size_t)seg*131072;

    for(int t=0;t<24;t++){
      // stage x = hv[:,t,:] from ring
      { int row=tid>>4, c8=(tid&15)*8;
        *(uint4*)(&Ast[row*136+c8]) = *(const uint4*)(BUF + ((size_t)((b0+row)*24+t))*128 + c8); }
      __syncthreads();
      bf16x8 ax[2][8];
      #pragma unroll
      for(int mt=0;mt<2;mt++)
        #pragma unroll
        for(int kt=0;kt<8;kt++)
          ax[mt][kt] = (kt<4)? *(const bf16x8*)(&Ast[(mt*16+l15)*136 + kt*32 + quad*8])
                             : *(const bf16x8*)(&hstash[(mt*16+l15)*136 + (kt-4)*32 + quad*8]);
      f32x4 acc[4][2];
      #pragma unroll
      for(int j=0;j<4;j++)
        #pragma unroll
        for(int mt=0;mt<2;mt++)
          #pragma unroll
          for(int r=0;r<4;r++) acc[j][mt][r]=be[j];
      #pragma unroll
      for(int kt=0;kt<8;kt++)
        #pragma unroll
        for(int j=0;j<4;j++){
          int nb=(wv+j*8)*16+l15;
          bf16x8 bf = *(const bf16x8*)(bbase + nb*256 + kt*32 + quad*8);
          #pragma unroll
          for(int mt=0;mt<2;mt++) acc[j][mt]=MFMA(ax[mt][kt], bf, acc[j][mt]);
        }
      // LSTM cell: i,f,g,o all lane-local (j = 0..3); c in registers
      u16 hnew[2][4];
      #pragma unroll
      for(int mt=0;mt<2;mt++)
        #pragma unroll
        for(int reg=0;reg<4;reg++){
          float ig=sig_(acc[0][mt][reg]), fg=sig_(acc[1][mt][reg]);
          float gg=th_(acc[2][mt][reg]),  og=sig_(acc[3][mt][reg]);
          float c_ = fg*cst[mt][reg] + ig*gg;
          cst[mt][reg]=c_;
          hnew[mt][reg] = f2b(og*th_(c_));
        }
      __syncthreads();
      #pragma unroll
      for(int mt=0;mt<2;mt++)
        #pragma unroll
        for(int reg=0;reg<4;reg++){
          int row=mt*16+quad*4+reg, hcol=wv*16+l15;
          u16 hb = hnew[mt][reg];
          hstash[row*136+hcol]=hb;
          BUF[((size_t)((b0+row)*24+t))*128+hcol]=hb;   // enc_out[:,t,:]
        }
      __syncthreads();
    }
  }

  // =============== decoder LSTM + projection ===============
  float bd[4];
  #pragma unroll
  for(int j=0;j<4;j++) bd[j]=decb[(wv+j*8)*16+l15];
  const u16* __restrict__ dbase = WU + DO_U;

  for(int t=0;t<24;t++){
    // stage query x-part [32][192]
    #pragma unroll
    for(int q=0;q<12;q++){
      int e = tid + 512*q; int row = e/192, kk = e - row*192; u16 v;
      if(kk<8)        v = f2b(tgt[(b0+row)*336 + cLAG[kk] + t]*invs[row]);
      else if(kk<12)  v = f2b(ptf[((size_t)((b0+row)*336+168+t))*4 + (kk-8)]);
      else if(kk<30)  v = statb[row][kk-12];
      else if(kk<32)  v = 0;
      else if(kk<160) v = BUF[((size_t)((b0+row)*24+t))*128 + (kk-32)];
      else if(kk<164) v = f2b(ftf[(b0+row)*96 + t*4 + (kk-160)]);
      else if(kk<182) v = statb[row][kk-164];
      else            v = 0;
      Ast[row*200+kk]=v;
    }
    __syncthreads();
    bf16x8 ax[2][10];
    #pragma unroll
    for(int mt=0;mt<2;mt++)
      #pragma unroll
      for(int kt=0;kt<10;kt++)
        ax[mt][kt] = (kt<6)? *(const bf16x8*)(&Ast[(mt*16+l15)*200 + kt*32 + quad*8])
                           : *(const bf16x8*)(&hstash[(mt*16+l15)*136 + (kt-6)*32 + quad*8]);
    f32x4 acc[4][2];
    #pragma unroll
    for(int j=0;j<4;j++)
      #pragma unroll
      for(int mt=0;mt<2;mt++)
        #pragma unroll
        for(int r=0;r<4;r++) acc[j][mt][r]=bd[j];
    #pragma unroll
    for(int kt=0;kt<10;kt++)
      #pragma unroll
      for(int j=0;j<4;j++){
        int nb=(wv+j*8)*16+l15;
        bf16x8 bf = *(const bf16x8*)(dbase + nb*320 + kt*32 + quad*8);
        #pragma unroll
        for(int mt=0;mt<2;mt++) acc[j][mt]=MFMA(ax[mt][kt], bf, acc[j][mt]);
      }
    u16 hnew[2][4];
    #pragma unroll
    for(int mt=0;mt<2;mt++)
      #pragma unroll
      for(int reg=0;reg<4;reg++){
        float ig=sig_(acc[0][mt][reg]), fg=sig_(acc[1][mt][reg]);
        float gg=th_(acc[2][mt][reg]),  og=sig_(acc[3][mt][reg]);
        float c_ = fg*cst[mt][reg] + ig*gg;
        cst[mt][reg]=c_;
        hnew[mt][reg] = f2b(og*th_(c_));
      }
    __syncthreads();
    #pragma unroll
    for(int mt=0;mt<2;mt++)
      #pragma unroll
      for(int reg=0;reg<4;reg++){
        int row=mt*16+quad*4+reg, hcol=wv*16+l15;
        hstash[row*136+hcol]=hnew[mt][reg];
      }
    __syncthreads();
    if(tid<256){
      int row=tid>>3, g=tid&7; float s=0.f;
      #pragma unroll
      for(int i=0;i<16;i++) s += b2f(hstash[row*136+g*16+i])*outw_s[g*16+i];
      red[row][g]=s;
    }
    __syncthreads();
    if(tid<32){
      float s=outb_s;
      #pragma unroll
      for(int g=0;g<8;g++) s+=red[tid][g];
      out[(b0+tid)*24+t]=s*scl[tid];
    }
    __syncthreads();
  }
}

extern "C" void kernel_launch(void* const* d_in, const int* in_sizes, int n_in,
                              void* d_out, int out_size, void* d_ws, size_t ws_size,
                              hipStream_t stream)
{
  (void)in_sizes; (void)n_in; (void)out_size; (void)ws_size;
  const int*   cat  = (const int*)d_in[0];
  const float* sreal= (const float*)d_in[1];
  const float* ptf  = (const float*)d_in[2];
  const float* tgt  = (const float*)d_in[3];
  const float* obs  = (const float*)d_in[4];
  const float* ftf  = (const float*)d_in[5];
  const float* emb  = (const float*)d_in[6];
  const float* gWih = (const float*)d_in[7];
  const float* gWhh = (const float*)d_in[8];
  const float* gbih = (const float*)d_in[9];
  const float* gbhh = (const float*)d_in[10];
  const float* eWih = (const float*)d_in[11];
  const float* eWhh = (const float*)d_in[12];
  const float* encb = (const float*)d_in[13];
  const float* dWih = (const float*)d_in[14];
  const float* dWhh = (const float*)d_in[15];
  const float* decb = (const float*)d_in[16];
  const float* outW = (const float*)d_in[17];
  const float* outb = (const float*)d_in[18];
  float* ws  = (float*)d_ws;
  float* out = (float*)d_out;

  hipMemsetAsync(d_ws, 0, 2*sizeof(float), stream);                       // global sums
  hipMemsetAsync((char*)d_ws + BUF_BYTE, 0, BUF_BYTES, stream);           // hv/enc ring = 0
  scale_kernel<<<dim3(8192/256), dim3(256), 0, stream>>>(tgt, obs, ws);
  prep_kernel<<<dim3(512), dim3(256), 0, stream>>>(gWih,gWhh,eWih,eWhh,dWih,dWhh,ws);
  deepar_mfma<<<dim3(256), dim3(512), 0, stream>>>(cat,sreal,ptf,tgt,ftf,emb,
                                                   gbih,gbhh,encb,decb,outW,outb,ws,out);
}

// Round 3
// 1507.858 us; speedup vs baseline: 15.4085x; 2.0843x over previous
//
#include <hip/hip_runtime.h>
#include <math.h>

typedef short bf16x8 __attribute__((ext_vector_type(8)));
typedef float f32x4 __attribute__((ext_vector_type(4)));
typedef unsigned short u16;
typedef unsigned int u32;

// float-region offsets in ws
#define WSUMS 0
#define TOTWS 1
#define WSUM_OFF 2
#define TOTW_OFF 8194
#define SCL_F 16386
#define WB_BYTE 98432      // start of bf16/u16 region (byte offset)

// u16-region offsets
#define GWI_U 0            // [384][32]   gru Wih (cols 0..29, pad 0)
#define GWH_U 12288        // [384][128]  gru Whh
#define EO_U  61440        // [7][512][256]  enc (Wih|Whh)
#define DO_U  978944       // [512][320]  dec packed
#define XG_U  1142784      // [7][8192][24][16] gru x feats (lags*inv, ptf, pad)
#define XD_U  23162880     // [8192][24][16]    dec x feats (lags*inv, ptf, ftf)
// end 26308608 u16 -> total ws ~52.7 MB (same as round-2 proven footprint)

__constant__ int cLAG[8] = {144,120,96,72,48,24,0,168};

__device__ __forceinline__ float sig_(float x){ return 1.0f/(1.0f+__expf(-x)); }
__device__ __forceinline__ float th_(float x){ float e=__expf(2.0f*x); return 1.0f - 2.0f/(e+1.0f); }
__device__ __forceinline__ u16 f2b(float x){ u32 u=__float_as_uint(x); return (u16)((u + 0x7fffu + ((u>>16)&1u))>>16); }
__device__ __forceinline__ float b2f(u16 v){ return __uint_as_float(((u32)v)<<16); }

#define MFMA(a,b,c) __builtin_amdgcn_mfma_f32_16x16x32_bf16(a,b,c,0,0,0)

__global__ void scale_kernel(const float* __restrict__ tgt,
                             const float* __restrict__ obs,
                             float* __restrict__ ws)
{
  __shared__ float s1[256], s2[256];
  int b = blockIdx.x*256 + threadIdx.x;
  float wsum=0.f, totw=0.f;
  const float* tr = tgt + b*336 + 168;
  const float* wr = obs + b*336 + 168;
  for(int t=0;t<168;t++){ float w=wr[t]; wsum += fabsf(tr[t])*w; totw += w; }
  ws[WSUM_OFF + b] = wsum;
  ws[TOTW_OFF + b] = totw;
  s1[threadIdx.x]=wsum; s2[threadIdx.x]=totw;
  __syncthreads();
  for(int s=128;s>0;s>>=1){
    if(threadIdx.x<s){ s1[threadIdx.x]+=s1[threadIdx.x+s]; s2[threadIdx.x]+=s2[threadIdx.x+s]; }
    __syncthreads();
  }
  if(threadIdx.x==0){ atomicAdd(&ws[WSUMS], s1[0]); atomicAdd(&ws[TOTWS], s2[0]); }
}

__global__ void prep_w(const float* __restrict__ gWih, const float* __restrict__ gWhh,
                       const float* __restrict__ eWih, const float* __restrict__ eWhh,
                       const float* __restrict__ dWih, const float* __restrict__ dWhh,
                       float* __restrict__ ws)
{
  u16* WU = (u16*)((char*)ws + WB_BYTE);
  int tid = blockIdx.x*blockDim.x + threadIdx.x;
  int nt = gridDim.x*blockDim.x;
  for(int i=tid;i<12288;i+=nt){ int n=i>>5,k=i&31; WU[GWI_U+i]=(k<30)?f2b(gWih[n*30+k]):(u16)0; }
  for(int i=tid;i<49152;i+=nt){ int n=i>>7,k=i&127; WU[GWH_U+i]=f2b(gWhh[n*128+k]); }
  for(int i=tid;i<917504;i+=nt){
    int s=i>>17,r2=i&131071,n=r2>>8,k=r2&255;
    float v=(k<128)?eWih[(s*512+n)*128+k]:eWhh[(s*512+n)*128+(k-128)];
    WU[EO_U+i]=f2b(v);
  }
  for(int i=tid;i<163840;i+=nt){
    int n=i/320, k=i-n*320; float v;
    if(k<128)       v=dWih[n*180+30+k];          // enc_out
    else if(k<136)  v=dWih[n*180+(k-128)];       // lags
    else if(k<140)  v=dWih[n*180+8+(k-136)];     // ptf
    else if(k<144)  v=dWih[n*180+158+(k-140)];   // ftf
    else if(k<162)  v=dWih[n*180+12+(k-144)];    // static (copy 1)
    else if(k<180)  v=dWih[n*180+162+(k-162)];   // static (copy 2)
    else if(k<192)  v=0.f;                        // pad
    else            v=dWhh[n*128+(k-192)];        // recurrent
    WU[DO_U+i]=f2b(v);
  }
}

__global__ void prep_x(const float* __restrict__ tgt, const float* __restrict__ ptf,
                       const float* __restrict__ ftf, float* __restrict__ ws)
{
  __shared__ float inv_l[64];
  u16* WU = (u16*)((char*)ws + WB_BYTE);
  const int tid = threadIdx.x;
  const int b0 = blockIdx.x*64;
  if(tid<64){
    int b=b0+tid;
    float wsumv=ws[WSUM_OFF+b], totw=ws[TOTW_OFF+b];
    float def=ws[WSUMS]/fmaxf(ws[TOTWS],1.f);
    float sc=fmaxf(1e-10f,(wsumv>0.f)?wsumv/fmaxf(totw,1.f):def);
    ws[SCL_F+b]=sc; inv_l[tid]=1.f/sc;
  }
  __syncthreads();
  for(int idx=tid; idx<64*168; idx+=256){
    int bl=idx/168, gt=idx-bl*168; int b=b0+bl;
    float iv=inv_l[bl];
    __align__(16) u16 row[16];
    #pragma unroll
    for(int j=0;j<8;j++) row[j]=f2b(tgt[b*336+cLAG[j]+gt]*iv);
    const float* pp=ptf+((size_t)(b*336+168+gt))*4;
    #pragma unroll
    for(int j=0;j<4;j++) row[8+j]=f2b(pp[j]);
    row[12]=row[13]=row[14]=row[15]=0;
    int seg=gt/24, t=gt-seg*24;
    u16* dst=WU+XG_U+(((size_t)seg*8192+b)*24+t)*16;
    *(uint4*)dst=*(const uint4*)row; *(uint4*)(dst+8)=*(const uint4*)(row+8);
  }
  for(int idx=tid; idx<64*24; idx+=256){
    int bl=idx/24, t=idx-bl*24; int b=b0+bl;
    float iv=inv_l[bl];
    __align__(16) u16 row[16];
    #pragma unroll
    for(int j=0;j<8;j++) row[j]=f2b(tgt[b*336+cLAG[j]+t]*iv);
    #pragma unroll
    for(int j=0;j<4;j++) row[8+j]=f2b(ptf[((size_t)(b*336+168+t))*4+j]);
    #pragma unroll
    for(int j=0;j<4;j++) row[12+j]=f2b(ftf[b*96+t*4+j]);
    u16* dst=WU+XD_U+((size_t)b*24+t)*16;
    *(uint4*)dst=*(const uint4*)row; *(uint4*)(dst+8)=*(const uint4*)(row+8);
  }
}

// beta(r,t) = (t>>2)*64 + r*4 + (t&3): row index into encbuf (t-group-major)
__global__ __launch_bounds__(512,2)
void deepar_main(const int* __restrict__ cat, const float* __restrict__ sreal,
                 const float* __restrict__ emb,
                 const float* __restrict__ gbih, const float* __restrict__ gbhh,
                 const float* __restrict__ encb, const float* __restrict__ decb,
                 const float* __restrict__ outW, const float* __restrict__ outb,
                 float* __restrict__ ws, float* __restrict__ out)
{
  const u16* __restrict__ WU=(const u16*)((const char*)ws+WB_BYTE);

  __shared__ __align__(16) u16 encbuf[384*136];   // enc_out / hv, in place (beta rows)
  __shared__ __align__(16) u16 Ast[16*136];       // per-step x-tile copy
  __shared__ __align__(16) u16 Xast[64*40];       // GRU x features tile
  __shared__ __align__(16) u16 Xdast[16*72];      // dec x features tile
  __shared__ __align__(16) u16 hstash[16*136];    // recurrent h (bf16)
  __shared__ u16 statb[16][18];
  __shared__ float scl_s[16];
  __shared__ float outw_s[128];
  __shared__ float red[16][8];
  __shared__ float outb_s;

  const int tid=threadIdx.x;
  const int b0=blockIdx.x*16;
  const int wv=tid>>6, lane=tid&63, quad=lane>>4, l15=lane&15;

  if(tid<16) scl_s[tid]=ws[SCL_F+b0+tid];
  if(tid<128) outw_s[tid]=outW[tid];
  if(tid==128) outb_s=outb[0];
  if(tid>=256){ int q=tid-256; int r=q>>4,k=q&15; statb[r][k]=f2b(emb[cat[b0+r]*16+k]); }
  for(int i=tid;i<384*136;i+=512) encbuf[i]=0;
  for(int i=tid;i<16*136;i+=512) hstash[i]=0;
  __syncthreads();
  if(tid<16){ statb[tid][16]=f2b(sreal[b0+tid]); statb[tid][17]=f2b(logf(scl_s[tid])); }
  __syncthreads();

  // ---- GRU weights: register-resident for entire kernel ----
  bf16x8 gwi[3]; bf16x8 gwh[3][4]; float gbi[3], gbh[3];
  #pragma unroll
  for(int j=0;j<3;j++){
    int nb=(wv+j*8)*16+l15;
    gwi[j]=*(const bf16x8*)(WU+GWI_U+nb*32+quad*8);
    #pragma unroll
    for(int kt=0;kt<4;kt++) gwh[j][kt]=*(const bf16x8*)(WU+GWH_U+nb*128+kt*32+quad*8);
    gbi[j]=gbih[nb]; gbh[j]=gbhh[nb];
  }

  float cst[4]={0.f,0.f,0.f,0.f};
  const int hc=wv*16+l15;

  for(int seg=0;seg<7;seg++){
    // ================= GRU: 6 chunks x 64 A-rows (16 r x 4 t), in place =================
    for(int c=0;c<6;c++){
      if(tid<64){
        int a=tid; int r=a>>2, tt=a&3;
        const u16* src=WU+XG_U+(((size_t)seg*8192+b0+r)*24+4*c+tt)*16;
        *(uint4*)(Xast+a*40)=*(const uint4*)src;          // cols 0..7 (lags)
        *(uint2*)(Xast+a*40+8)=*(const uint2*)(src+8);    // cols 8..11 (ptf)
        #pragma unroll
        for(int j=0;j<18;j++) Xast[a*40+12+j]=statb[r][j];
        Xast[a*40+30]=0; Xast[a*40+31]=0;
      }
      __syncthreads();

      f32x4 ai[3][4], ah[3][4];
      #pragma unroll
      for(int j=0;j<3;j++)
        #pragma unroll
        for(int mt=0;mt<4;mt++){
          ai[j][mt]=(f32x4){gbi[j],gbi[j],gbi[j],gbi[j]};
          ah[j][mt]=(f32x4){gbh[j],gbh[j],gbh[j],gbh[j]};
        }
      #pragma unroll
      for(int mt=0;mt<4;mt++){
        bf16x8 af=*(const bf16x8*)(Xast+(mt*16+l15)*40+quad*8);
        #pragma unroll
        for(int j=0;j<3;j++) ai[j][mt]=MFMA(af,gwi[j],ai[j][mt]);
      }
      const u16* ebase=encbuf+(size_t)(c*64)*136;
      #pragma unroll
      for(int kt=0;kt<4;kt++)
        #pragma unroll
        for(int mt=0;mt<4;mt++){
          bf16x8 af=*(const bf16x8*)(ebase+(mt*16+l15)*136+kt*32+quad*8);
          #pragma unroll
          for(int j=0;j<3;j++) ah[j][mt]=MFMA(af,gwh[j][kt],ah[j][mt]);
        }
      u16 hv16[4][4];
      #pragma unroll
      for(int mt=0;mt<4;mt++)
        #pragma unroll
        for(int reg=0;reg<4;reg++){
          int a=mt*16+quad*4+reg;
          float rg=sig_(ai[0][mt][reg]+ah[0][mt][reg]);
          float zg=sig_(ai[1][mt][reg]+ah[1][mt][reg]);
          float hp=b2f(encbuf[(c*64+a)*136+hc]);
          float nn=th_(ai[2][mt][reg]+rg*ah[2][mt][reg]);
          hv16[mt][reg]=f2b((1.f-zg)*nn+zg*hp);
        }
      __syncthreads();   // all reads of these rows done before overwrite
      #pragma unroll
      for(int mt=0;mt<4;mt++)
        #pragma unroll
        for(int reg=0;reg<4;reg++)
          encbuf[(c*64+mt*16+quad*4+reg)*136+hc]=hv16[mt][reg];
    }
    __syncthreads();     // hv complete before LSTM consumes

    // ================= encoder LSTM: weights -> registers, 24 steps =================
    bf16x8 we[4][8]; float be[4];
    #pragma unroll
    for(int j=0;j<4;j++){
      int nb=(wv+j*8)*16+l15;
      be[j]=encb[seg*512+nb];
      #pragma unroll
      for(int kt=0;kt<8;kt++)
        we[j][kt]=*(const bf16x8*)(WU+EO_U+(size_t)seg*131072+nb*256+kt*32+quad*8);
    }
    for(int t=0;t<24;t++){
      int tb=(t>>2)*64+(t&3);
      if(tid<256){ int row=tid>>4,q=tid&15;
        *(uint4*)(Ast+row*136+q*8)=*(const uint4*)(encbuf+(tb+row*4)*136+q*8); }
      __syncthreads();
      f32x4 acc[4];
      #pragma unroll
      for(int j=0;j<4;j++) acc[j]=(f32x4){be[j],be[j],be[j],be[j]};
      #pragma unroll
      for(int kt=0;kt<8;kt++){
        bf16x8 af=(kt<4)? *(const bf16x8*)(Ast+l15*136+kt*32+quad*8)
                        : *(const bf16x8*)(hstash+l15*136+(kt-4)*32+quad*8);
        #pragma unroll
        for(int j=0;j<4;j++) acc[j]=MFMA(af,we[j][kt],acc[j]);
      }
      u16 hnew[4];
      #pragma unroll
      for(int reg=0;reg<4;reg++){
        float ig=sig_(acc[0][reg]),fg=sig_(acc[1][reg]);
        float gg=th_(acc[2][reg]), og=sig_(acc[3][reg]);
        float c_=fg*cst[reg]+ig*gg; cst[reg]=c_;
        hnew[reg]=f2b(og*th_(c_));
      }
      __syncthreads();   // frag reads done before writes
      #pragma unroll
      for(int reg=0;reg<4;reg++){
        int row=quad*4+reg;
        hstash[row*136+hc]=hnew[reg];
        encbuf[(tb+row*4)*136+hc]=hnew[reg];
      }
    }
    __syncthreads();
  }

  // ================= decoder LSTM + projection =================
  bf16x8 wd[4][10]; float bd[4];
  #pragma unroll
  for(int j=0;j<4;j++){
    int nb=(wv+j*8)*16+l15;
    bd[j]=decb[nb];
    #pragma unroll
    for(int kt=0;kt<10;kt++)
      wd[j][kt]=*(const bf16x8*)(WU+DO_U+nb*320+kt*32+quad*8);
  }
  for(int t=0;t<24;t++){
    int tb=(t>>2)*64+(t&3);
    if(tid<256){ int row=tid>>4,q=tid&15;
      *(uint4*)(Ast+row*136+q*8)=*(const uint4*)(encbuf+(tb+row*4)*136+q*8); }
    else if(tid<272){
      int row=tid-256;
      const u16* src=WU+XD_U+((size_t)(b0+row)*24+t)*16;
      *(uint4*)(Xdast+row*72)=*(const uint4*)src;
      *(uint4*)(Xdast+row*72+8)=*(const uint4*)(src+8);
      #pragma unroll
      for(int j=0;j<18;j++){ u16 s=statb[row][j]; Xdast[row*72+16+j]=s; Xdast[row*72+34+j]=s; }
      #pragma unroll
      for(int j=52;j<64;j++) Xdast[row*72+j]=0;
    }
    __syncthreads();
    f32x4 acc[4];
    #pragma unroll
    for(int j=0;j<4;j++) acc[j]=(f32x4){bd[j],bd[j],bd[j],bd[j]};
    #pragma unroll
    for(int kt=0;kt<10;kt++){
      bf16x8 af=(kt<4)? *(const bf16x8*)(Ast+l15*136+kt*32+quad*8)
              :(kt<6)? *(const bf16x8*)(Xdast+l15*72+(kt-4)*32+quad*8)
                     : *(const bf16x8*)(hstash+l15*136+(kt-6)*32+quad*8);
      #pragma unroll
      for(int j=0;j<4;j++) acc[j]=MFMA(af,wd[j][kt],acc[j]);
    }
    u16 hnew[4];
    #pragma unroll
    for(int reg=0;reg<4;reg++){
      float ig=sig_(acc[0][reg]),fg=sig_(acc[1][reg]);
      float gg=th_(acc[2][reg]), og=sig_(acc[3][reg]);
      float c_=fg*cst[reg]+ig*gg; cst[reg]=c_;
      hnew[reg]=f2b(og*th_(c_));
    }
    __syncthreads();
    #pragma unroll
    for(int reg=0;reg<4;reg++){
      int row=quad*4+reg;
      hstash[row*136+hc]=hnew[reg];
    }
    __syncthreads();
    if(tid<128){ int row=tid>>3,g=tid&7; float s=0.f;
      #pragma unroll
      for(int i=0;i<16;i++) s+=b2f(hstash[row*136+g*16+i])*outw_s[g*16+i];
      red[row][g]=s; }
    __syncthreads();
    if(tid<16){ float s=outb_s;
      #pragma unroll
      for(int g=0;g<8;g++) s+=red[tid][g];
      out[(b0+tid)*24+t]=s*scl_s[tid]; }
    __syncthreads();
  }
}

extern "C" void kernel_launch(void* const* d_in, const int* in_sizes, int n_in,
                              void* d_out, int out_size, void* d_ws, size_t ws_size,
                              hipStream_t stream)
{
  (void)in_sizes; (void)n_in; (void)out_size; (void)ws_size;
  const int*   cat  = (const int*)d_in[0];
  const float* sreal= (const float*)d_in[1];
  const float* ptf  = (const float*)d_in[2];
  const float* tgt  = (const float*)d_in[3];
  const float* obs  = (const float*)d_in[4];
  const float* ftf  = (const float*)d_in[5];
  const float* emb  = (const float*)d_in[6];
  const float* gWih = (const float*)d_in[7];
  const float* gWhh = (const float*)d_in[8];
  const float* gbih = (const float*)d_in[9];
  const float* gbhh = (const float*)d_in[10];
  const float* eWih = (const float*)d_in[11];
  const float* eWhh = (const float*)d_in[12];
  const float* encb = (const float*)d_in[13];
  const float* dWih = (const float*)d_in[14];
  const float* dWhh = (const float*)d_in[15];
  const float* decb = (const float*)d_in[16];
  const float* outW = (const float*)d_in[17];
  const float* outb = (const float*)d_in[18];
  float* ws  = (float*)d_ws;
  float* out = (float*)d_out;

  hipMemsetAsync(d_ws, 0, 2*sizeof(float), stream);
  scale_kernel<<<dim3(8192/256), dim3(256), 0, stream>>>(tgt, obs, ws);
  prep_w<<<dim3(512), dim3(256), 0, stream>>>(gWih,gWhh,eWih,eWhh,dWih,dWhh,ws);
  prep_x<<<dim3(128), dim3(256), 0, stream>>>(tgt, ptf, ftf, ws);
  deepar_main<<<dim3(512), dim3(512), 0, stream>>>(cat,sreal,emb,gbih,gbhh,encb,decb,
                                                   outW,outb,ws,out);
}

// Round 5
// 1429.279 us; speedup vs baseline: 16.2556x; 1.0550x over previous
//
#include <hip/hip_runtime.h>
#include <math.h>

typedef short bf16x8 __attribute__((ext_vector_type(8)));
typedef float f32x4 __attribute__((ext_vector_type(4)));
typedef unsigned short u16;
typedef unsigned int u32;

// float-region offsets in ws
#define WSUMS 0
#define TOTWS 1
#define WSUM_OFF 2
#define TOTW_OFF 8194
#define SCL_F 16386
#define WB_BYTE 98432      // start of bf16/u16 region (byte offset)

// u16-region offsets
#define GWI_U 0            // [384][32]   gru Wih (cols 0..29, pad 0)
#define GWH_U 12288        // [384][128]  gru Whh
#define EO_U  61440        // [7][512][256]  enc (Wih|Whh)
#define DO_U  978944       // [512][320]  dec packed
#define XG_U  1142784      // [7][8192][24][16] gru x feats
#define XD_U  23162880     // [8192][24][16]    dec x feats

__constant__ int cLAG[8] = {144,120,96,72,48,24,0,168};

__device__ __forceinline__ float sig_(float x){ return 1.0f/(1.0f+__expf(-x)); }
__device__ __forceinline__ float th_(float x){ float e=__expf(2.0f*x); return 1.0f - 2.0f/(e+1.0f); }
__device__ __forceinline__ u16 f2b(float x){ u32 u=__float_as_uint(x); return (u16)((u + 0x7fffu + ((u>>16)&1u))>>16); }
__device__ __forceinline__ float b2f(u16 v){ return __uint_as_float(((u32)v)<<16); }
// Pin a fragment into VGPRs: opaque asm forces materialization outside loops.
__device__ __forceinline__ void pin(bf16x8 &x){
  f32x4 t = __builtin_bit_cast(f32x4, x);
  asm volatile("" : "+v"(t));
  x = __builtin_bit_cast(bf16x8, t);
}

#define MFMA(a,b,c) __builtin_amdgcn_mfma_f32_16x16x32_bf16(a,b,c,0,0,0)

__global__ void scale_kernel(const float* __restrict__ tgt,
                             const float* __restrict__ obs,
                             float* __restrict__ ws)
{
  __shared__ float s1[256], s2[256];
  int b = blockIdx.x*256 + threadIdx.x;
  float wsum=0.f, totw=0.f;
  const float* tr = tgt + b*336 + 168;
  const float* wr = obs + b*336 + 168;
  for(int t=0;t<168;t++){ float w=wr[t]; wsum += fabsf(tr[t])*w; totw += w; }
  ws[WSUM_OFF + b] = wsum;
  ws[TOTW_OFF + b] = totw;
  s1[threadIdx.x]=wsum; s2[threadIdx.x]=totw;
  __syncthreads();
  for(int s=128;s>0;s>>=1){
    if(threadIdx.x<s){ s1[threadIdx.x]+=s1[threadIdx.x+s]; s2[threadIdx.x]+=s2[threadIdx.x+s]; }
    __syncthreads();
  }
  if(threadIdx.x==0){ atomicAdd(&ws[WSUMS], s1[0]); atomicAdd(&ws[TOTWS], s2[0]); }
}

__global__ void prep_w(const float* __restrict__ gWih, const float* __restrict__ gWhh,
                       const float* __restrict__ eWih, const float* __restrict__ eWhh,
                       const float* __restrict__ dWih, const float* __restrict__ dWhh,
                       float* __restrict__ ws)
{
  u16* WU = (u16*)((char*)ws + WB_BYTE);
  int tid = blockIdx.x*blockDim.x + threadIdx.x;
  int nt = gridDim.x*blockDim.x;
  for(int i=tid;i<12288;i+=nt){ int n=i>>5,k=i&31; WU[GWI_U+i]=(k<30)?f2b(gWih[n*30+k]):(u16)0; }
  for(int i=tid;i<49152;i+=nt){ int n=i>>7,k=i&127; WU[GWH_U+i]=f2b(gWhh[n*128+k]); }
  for(int i=tid;i<917504;i+=nt){
    int s=i>>17,r2=i&131071,n=r2>>8,k=r2&255;
    float v=(k<128)?eWih[(s*512+n)*128+k]:eWhh[(s*512+n)*128+(k-128)];
    WU[EO_U+i]=f2b(v);
  }
  for(int i=tid;i<163840;i+=nt){
    int n=i/320, k=i-n*320; float v;
    if(k<128)       v=dWih[n*180+30+k];
    else if(k<136)  v=dWih[n*180+(k-128)];
    else if(k<140)  v=dWih[n*180+8+(k-136)];
    else if(k<144)  v=dWih[n*180+158+(k-140)];
    else if(k<162)  v=dWih[n*180+12+(k-144)];
    else if(k<180)  v=dWih[n*180+162+(k-162)];
    else if(k<192)  v=0.f;
    else            v=dWhh[n*128+(k-192)];
    WU[DO_U+i]=f2b(v);
  }
}

__global__ void prep_x(const float* __restrict__ tgt, const float* __restrict__ ptf,
                       const float* __restrict__ ftf, float* __restrict__ ws)
{
  __shared__ float inv_l[64];
  u16* WU = (u16*)((char*)ws + WB_BYTE);
  const int tid = threadIdx.x;
  const int b0 = blockIdx.x*64;
  if(tid<64){
    int b=b0+tid;
    float wsumv=ws[WSUM_OFF+b], totw=ws[TOTW_OFF+b];
    float def=ws[WSUMS]/fmaxf(ws[TOTWS],1.f);
    float sc=fmaxf(1e-10f,(wsumv>0.f)?wsumv/fmaxf(totw,1.f):def);
    ws[SCL_F+b]=sc; inv_l[tid]=1.f/sc;
  }
  __syncthreads();
  for(int idx=tid; idx<64*168; idx+=256){
    int bl=idx/168, gt=idx-bl*168; int b=b0+bl;
    float iv=inv_l[bl];
    __align__(16) u16 row[16];
    #pragma unroll
    for(int j=0;j<8;j++) row[j]=f2b(tgt[b*336+cLAG[j]+gt]*iv);
    const float* pp=ptf+((size_t)(b*336+168+gt))*4;
    #pragma unroll
    for(int j=0;j<4;j++) row[8+j]=f2b(pp[j]);
    row[12]=row[13]=row[14]=row[15]=0;
    int seg=gt/24, t=gt-seg*24;
    u16* dst=WU+XG_U+(((size_t)seg*8192+b)*24+t)*16;
    *(uint4*)dst=*(const uint4*)row; *(uint4*)(dst+8)=*(const uint4*)(row+8);
  }
  for(int idx=tid; idx<64*24; idx+=256){
    int bl=idx/24, t=idx-bl*24; int b=b0+bl;
    float iv=inv_l[bl];
    __align__(16) u16 row[16];
    #pragma unroll
    for(int j=0;j<8;j++) row[j]=f2b(tgt[b*336+cLAG[j]+t]*iv);
    #pragma unroll
    for(int j=0;j<4;j++) row[8+j]=f2b(ptf[((size_t)(b*336+168+t))*4+j]);
    #pragma unroll
    for(int j=0;j<4;j++) row[12+j]=f2b(ftf[b*96+t*4+j]);
    u16* dst=WU+XD_U+((size_t)b*24+t)*16;
    *(uint4*)dst=*(const uint4*)row; *(uint4*)(dst+8)=*(const uint4*)(row+8);
  }
}

// beta(r,t) = (t>>2)*64 + r*4 + (t&3): encbuf row index (t-group-major)
__global__ __launch_bounds__(512,2)
void deepar_main(const int* __restrict__ cat, const float* __restrict__ sreal,
                 const float* __restrict__ emb,
                 const float* __restrict__ gbih, const float* __restrict__ gbhh,
                 const float* __restrict__ encb, const float* __restrict__ decb,
                 const float* __restrict__ outW, const float* __restrict__ outb,
                 float* __restrict__ ws, float* __restrict__ out)
{
  const u16* __restrict__ WU=(const u16*)((const char*)ws+WB_BYTE);

  __shared__ __align__(16) u16 encbuf[384*136];   // enc_out / hv, in place (beta rows)
  __shared__ __align__(16) u16 Ast[2][16*136];    // enc/dec x-tile, double-buffered
  __shared__ __align__(16) u16 Xast[2][64*40];    // GRU x tile (statics prebuilt)
  __shared__ __align__(16) u16 Xdast[16*72];      // dec extra feats (statics prebuilt)
  __shared__ __align__(16) u16 hstash[2][16*136]; // recurrent h, double-buffered
  __shared__ u16 statb[16][18];
  __shared__ float scl_s[16];
  __shared__ float outw_s[128];
  __shared__ float red[16][8];
  __shared__ float outb_s;

  const int tid=threadIdx.x;
  const int b0=blockIdx.x*16;
  const int wv=tid>>6, lane=tid&63, quad=lane>>4, l15=lane&15;

  if(tid<16) scl_s[tid]=ws[SCL_F+b0+tid];
  if(tid<128) outw_s[tid]=outW[tid];
  if(tid==128) outb_s=outb[0];
  if(tid>=256){ int q=tid-256; int r=q>>4,k=q&15; statb[r][k]=f2b(emb[cat[b0+r]*16+k]); }
  { const uint4 z4={0,0,0,0};
    for(int i=tid;i<6528;i+=512) *(uint4*)(encbuf+i*8)=z4;   // 6528*8 = 384*136 exactly
    for(int i=tid;i<544;i+=512)  *(uint4*)(&hstash[0][0]+i*8)=z4; // 544*8 = 2*16*136 exactly
  }
  __syncthreads();
  if(tid<16){ statb[tid][16]=f2b(sreal[b0+tid]); statb[tid][17]=f2b(logf(scl_s[tid])); }
  __syncthreads();
  // prebuild t-invariant columns of GRU / dec A-tiles
  for(int i=tid;i<1280;i+=512){ int a=i/20, k=i-a*20+12;
    u16 v=(k<30)?statb[a>>2][k-12]:(u16)0;
    Xast[0][a*40+k]=v; Xast[1][a*40+k]=v; }
  for(int i=tid;i<896;i+=512){ int rr=i/56, k=i-rr*56+16;
    u16 v; if(k<34) v=statb[rr][k-16]; else if(k<52) v=statb[rr][k-34]; else v=0;
    Xdast[rr*72+k]=v; }
  __syncthreads();

  float gbi[3], gbh[3];
  #pragma unroll
  for(int j=0;j<3;j++){ int nb=(wv+j*8)*16+l15; gbi[j]=gbih[nb]; gbh[j]=gbhh[nb]; }

  float cst[4]={0.f,0.f,0.f,0.f};
  const int hc=wv*16+l15;
  int p=0;                                  // hstash parity

  for(int seg=0;seg<7;seg++){
    // ---- GRU weights: load + pin (live this phase only) ----
    bf16x8 gwi[3]; bf16x8 gwh[3][4];
    #pragma unroll
    for(int j=0;j<3;j++){
      int nb=(wv+j*8)*16+l15;
      gwi[j]=*(const bf16x8*)(WU+GWI_U+nb*32+quad*8); pin(gwi[j]);
      #pragma unroll
      for(int kt=0;kt<4;kt++){ gwh[j][kt]=*(const bf16x8*)(WU+GWH_U+nb*128+kt*32+quad*8); pin(gwh[j][kt]); }
    }

    // ================= GRU: 6 chunks x 64 A-rows (16 r x 4 t), in place =================
    for(int c=0;c<6;c++){
      u16* Xb = &Xast[c&1][0];
      if(tid<128){ int a=tid>>1;
        const u16* src=WU+XG_U+(((size_t)seg*8192+b0+(a>>2))*24+4*c+(a&3))*16;
        if(tid&1) *(uint2*)(Xb+a*40+8)=*(const uint2*)(src+8);
        else      *(uint4*)(Xb+a*40)  =*(const uint4*)src; }
      __syncthreads();

      f32x4 ai[3][4], ah[3][4];
      #pragma unroll
      for(int j=0;j<3;j++)
        #pragma unroll
        for(int mt=0;mt<4;mt++){
          ai[j][mt]=(f32x4){gbi[j],gbi[j],gbi[j],gbi[j]};
          ah[j][mt]=(f32x4){gbh[j],gbh[j],gbh[j],gbh[j]};
        }
      #pragma unroll
      for(int mt=0;mt<4;mt++){
        bf16x8 af=*(const bf16x8*)(Xb+(mt*16+l15)*40+quad*8);
        #pragma unroll
        for(int j=0;j<3;j++) ai[j][mt]=MFMA(af,gwi[j],ai[j][mt]);
      }
      const u16* ebase=encbuf+(size_t)(c*64)*136;
      #pragma unroll
      for(int kt=0;kt<4;kt++)
        #pragma unroll
        for(int mt=0;mt<4;mt++){
          bf16x8 af=*(const bf16x8*)(ebase+(mt*16+l15)*136+kt*32+quad*8);
          #pragma unroll
          for(int j=0;j<3;j++) ah[j][mt]=MFMA(af,gwh[j][kt],ah[j][mt]);
        }
      u16 hv16[4][4];
      #pragma unroll
      for(int mt=0;mt<4;mt++)
        #pragma unroll
        for(int reg=0;reg<4;reg++){
          int a=mt*16+quad*4+reg;
          float rg=sig_(ai[0][mt][reg]+ah[0][mt][reg]);
          float zg=sig_(ai[1][mt][reg]+ah[1][mt][reg]);
          float hp=b2f(encbuf[(c*64+a)*136+hc]);
          float nn=th_(ai[2][mt][reg]+rg*ah[2][mt][reg]);
          hv16[mt][reg]=f2b((1.f-zg)*nn+zg*hp);
        }
      __syncthreads();   // all reads of rows c done before in-place overwrite
      #pragma unroll
      for(int mt=0;mt<4;mt++)
        #pragma unroll
        for(int reg=0;reg<4;reg++)
          encbuf[(c*64+mt*16+quad*4+reg)*136+hc]=hv16[mt][reg];
    }

    // ================= encoder LSTM: pinned weights, 1 barrier/step =================
    bf16x8 we[4][8]; float be[4];
    #pragma unroll
    for(int j=0;j<4;j++){
      int nb=(wv+j*8)*16+l15;
      be[j]=encb[seg*512+nb];
      #pragma unroll
      for(int kt=0;kt<8;kt++){
        we[j][kt]=*(const bf16x8*)(WU+EO_U+(size_t)seg*131072+nb*256+kt*32+quad*8);
        pin(we[j][kt]);
      }
    }
    for(int t=0;t<24;t++){
      int tb=(t>>2)*64+(t&3);
      u16* Ab=&Ast[t&1][0];
      // stage(t): reads rows(t) written >=1 barrier ago; disjoint from writes(t) below
      if(tid<256){ int row=tid>>4,q=tid&15;
        *(uint4*)(Ab+row*136+q*8)=*(const uint4*)(encbuf+(tb+row*4)*136+q*8); }
      __syncthreads();
      const u16* Hb=&hstash[p][0];
      f32x4 acc[4];
      #pragma unroll
      for(int j=0;j<4;j++) acc[j]=(f32x4){be[j],be[j],be[j],be[j]};
      #pragma unroll
      for(int kt=0;kt<8;kt++){
        bf16x8 af=(kt<4)? *(const bf16x8*)(Ab+l15*136+kt*32+quad*8)
                        : *(const bf16x8*)(Hb+l15*136+(kt-4)*32+quad*8);
        #pragma unroll
        for(int j=0;j<4;j++) acc[j]=MFMA(af,we[j][kt],acc[j]);
      }
      u16 hnew[4];
      #pragma unroll
      for(int reg=0;reg<4;reg++){
        float ig=sig_(acc[0][reg]),fg=sig_(acc[1][reg]);
        float gg=th_(acc[2][reg]), og=sig_(acc[3][reg]);
        float c_=fg*cst[reg]+ig*gg; cst[reg]=c_;
        hnew[reg]=f2b(og*th_(c_));
      }
      int pn=p^1;
      u16* Hw=&hstash[pn][0];
      #pragma unroll
      for(int reg=0;reg<4;reg++){
        int row=quad*4+reg;
        Hw[row*136+hc]=hnew[reg];            // opposite buffer: no read hazard
        encbuf[(tb+row*4)*136+hc]=hnew[reg]; // rows(t): staged pre-barrier, safe
      }
      p=pn;
    }
  }

  // ================= decoder LSTM + projection =================
  bf16x8 wd[4][10]; float bd[4];
  #pragma unroll
  for(int j=0;j<4;j++){
    int nb=(wv+j*8)*16+l15;
    bd[j]=decb[nb];
    #pragma unroll
    for(int kt=0;kt<10;kt++){
      wd[j][kt]=*(const bf16x8*)(WU+DO_U+nb*320+kt*32+quad*8);
      pin(wd[j][kt]);
    }
  }
  for(int t=0;t<24;t++){
    int tb=(t>>2)*64+(t&3);
    u16* Ab=&Ast[t&1][0];
    if(tid<256){ int row=tid>>4,q=tid&15;
      *(uint4*)(Ab+row*136+q*8)=*(const uint4*)(encbuf+(tb+row*4)*136+q*8); }
    else if(tid<288){ int q=tid-256; int rr=q>>1;
      const u16* src=WU+XD_U+((size_t)(b0+rr)*24+t)*16;
      if(q&1) *(uint4*)(Xdast+rr*72+8)=*(const uint4*)(src+8);
      else    *(uint4*)(Xdast+rr*72)  =*(const uint4*)src; }
    __syncthreads();
    const u16* Hb=&hstash[p][0];
    f32x4 acc[4];
    #pragma unroll
    for(int j=0;j<4;j++) acc[j]=(f32x4){bd[j],bd[j],bd[j],bd[j]};
    #pragma unroll
    for(int kt=0;kt<10;kt++){
      bf16x8 af=(kt<4)? *(const bf16x8*)(Ab+l15*136+kt*32+quad*8)
              :(kt<6)? *(const bf16x8*)(Xdast+l15*72+(kt-4)*32+quad*8)
                     : *(const bf16x8*)(Hb+l15*136+(kt-6)*32+quad*8);
      #pragma unroll
      for(int j=0;j<4;j++) acc[j]=MFMA(af,wd[j][kt],acc[j]);
    }
    u16 hnew[4];
    #pragma unroll
    for(int reg=0;reg<4;reg++){
      float ig=sig_(acc[0][reg]),fg=sig_(acc[1][reg]);
      float gg=th_(acc[2][reg]), og=sig_(acc[3][reg]);
      float c_=fg*cst[reg]+ig*gg; cst[reg]=c_;
      hnew[reg]=f2b(og*th_(c_));
    }
    int pn=p^1;
    #pragma unroll
    for(int reg=0;reg<4;reg++)
      hstash[pn][(quad*4+reg)*136+hc]=hnew[reg];
    __syncthreads();      // projection needs the full new h row
    if(tid<128){ int row=tid>>3,g=tid&7; float s=0.f;
      #pragma unroll
      for(int i=0;i<16;i++) s+=b2f(hstash[pn][row*136+g*16+i])*outw_s[g*16+i];
      red[row][g]=s; }
    __syncthreads();
    if(tid<16){ float s=outb_s;
      #pragma unroll
      for(int g=0;g<8;g++) s+=red[tid][g];
      out[(b0+tid)*24+t]=s*scl_s[tid]; }
    p=pn;
  }
}

extern "C" void kernel_launch(void* const* d_in, const int* in_sizes, int n_in,
                              void* d_out, int out_size, void* d_ws, size_t ws_size,
                              hipStream_t stream)
{
  (void)in_sizes; (void)n_in; (void)out_size; (void)ws_size;
  const int*   cat  = (const int*)d_in[0];
  const float* sreal= (const float*)d_in[1];
  const float* ptf  = (const float*)d_in[2];
  const float* tgt  = (const float*)d_in[3];
  const float* obs  = (const float*)d_in[4];
  const float* ftf  = (const float*)d_in[5];
  const float* emb  = (const float*)d_in[6];
  const float* gWih = (const float*)d_in[7];
  const float* gWhh = (const float*)d_in[8];
  const float* gbih = (const float*)d_in[9];
  const float* gbhh = (const float*)d_in[10];
  const float* eWih = (const float*)d_in[11];
  const float* eWhh = (const float*)d_in[12];
  const float* encb = (const float*)d_in[13];
  const float* dWih = (const float*)d_in[14];
  const float* dWhh = (const float*)d_in[15];
  const float* decb = (const float*)d_in[16];
  const float* outW = (const float*)d_in[17];
  const float* outb = (const float*)d_in[18];
  float* ws  = (float*)d_ws;
  float* out = (float*)d_out;

  hipMemsetAsync(d_ws, 0, 2*sizeof(float), stream);
  scale_kernel<<<dim3(8192/256), dim3(256), 0, stream>>>(tgt, obs, ws);
  prep_w<<<dim3(512), dim3(256), 0, stream>>>(gWih,gWhh,eWih,eWhh,dWih,dWhh,ws);
  prep_x<<<dim3(128), dim3(256), 0, stream>>>(tgt, ptf, ftf, ws);
  deepar_main<<<dim3(512), dim3(512), 0, stream>>>(cat,sreal,emb,gbih,gbhh,encb,decb,
                                                   outW,outb,ws,out);
}